// Round 7
// baseline (440.335 us; speedup 1.0000x reference)
//
#include <hip/hip_runtime.h>
#include <hip/hip_fp16.h>

// GAT (3-layer) on MI355X. N=50000 nodes, E=800000 edges, D=64, H=2/2/1.
// R13: k_agg plateau (42-46us across R7/R9/R12 regardless of VALU mix) is the
//      one-wave-per-node latency regime: deg~16 -> ~4-step dependent gather
//      chain per wave, exposed miss latency. Rewrite EDGE-MAJOR: block owns 64
//      consecutive nodes (contiguous edge range ~1024 edges); 16 lane-groups
//      stream ~64 edges each (deep loop = intra-wave latency hiding); dst-runs
//      accumulate alpha*F in registers, flush to LDS acc via atomicAdd(shared
//      f32, native ds_add) on dst change (~4 flushes/group). alpha computed
//      inline from L2-resident elr -> k_alpha kernels + ealpha buffer deleted.
//      Finalize: barrier, normalize+bias+res+act+store from LDS.

typedef __attribute__((ext_vector_type(8))) short short8;   // 8 bf16 (4 VGPRs)
typedef __attribute__((ext_vector_type(4))) float float4v;  // 4 fp32 acc

__device__ __forceinline__ float lrelu(float x){ return fmaxf(x, 0.2f*x); }

__device__ __forceinline__ unsigned short f2bf(float f){   // RNE round
  unsigned int u = __float_as_uint(f);
  u += 0x7fffu + ((u >> 16) & 1u);
  return (unsigned short)(u >> 16);
}
__device__ __forceinline__ unsigned short f2h(float f){
  return __half_as_ushort(__float2half(f));
}
__device__ __forceinline__ float elu1(float x){            // elu, x<0 branch via exp
  return x > 0.f ? x : (__expf(x) - 1.f);
}

__global__ void k_zero_i32(int* __restrict__ p, int n){
  int i = blockIdx.x*blockDim.x + threadIdx.x;
  if (i < n) p[i] = 0;
}

// hist + rank in one atomic: rank[i] = position of edge i within its dst bucket
__global__ void k_hist_rank(const int* __restrict__ dst, int* __restrict__ counts,
                            int* __restrict__ rank, int E){
  int i = blockIdx.x*blockDim.x + threadIdx.x;
  if (i < E){
    int d = dst[i];
    rank[i] = atomicAdd(&counts[d], 1);
  }
}

__global__ void k_scan_local(const int* __restrict__ counts, int* __restrict__ row_ptr,
                             int* __restrict__ bsum, int N){
  __shared__ int s[256];
  int t = threadIdx.x, g = blockIdx.x*256 + t;
  int v = (g < N) ? counts[g] : 0;
  s[t] = v; __syncthreads();
  #pragma unroll
  for (int off = 1; off < 256; off <<= 1){
    int x = 0;
    if (t >= off) x = s[t-off];
    __syncthreads();
    s[t] += x;
    __syncthreads();
  }
  if (g < N) row_ptr[g+1] = s[t];
  if (g == 0 && t == 0) row_ptr[0] = 0;
  if (t == 255) bsum[blockIdx.x] = s[255];
}

__global__ void k_scan_top(int* __restrict__ bsum, int nb){
  __shared__ int s[256];
  int t = threadIdx.x;
  int v = (t < nb) ? bsum[t] : 0;
  s[t] = v; __syncthreads();
  #pragma unroll
  for (int off = 1; off < 256; off <<= 1){
    int x = 0;
    if (t >= off) x = s[t-off];
    __syncthreads();
    s[t] += x;
    __syncthreads();
  }
  if (t < nb) bsum[t] = s[t] - v;  // exclusive block offsets
}

__global__ void k_scan_fix(int* __restrict__ row_ptr, const int* __restrict__ bsum, int N){
  int g = blockIdx.x*256 + threadIdx.x;
  if (g < N && blockIdx.x > 0) row_ptr[g+1] += bsum[blockIdx.x];
}

// atomic-free scatter: pos comes from rank captured during hist; also emits sdst
__global__ void k_scatter2(const int* __restrict__ src, const int* __restrict__ dst,
                           const int* __restrict__ rank, const int* __restrict__ row_ptr,
                           int* __restrict__ ssrc, int* __restrict__ sdst, int E){
  int i = blockIdx.x*blockDim.x + threadIdx.x;
  if (i < E){
    int d = dst[i];
    int p = row_ptr[d] + rank[i];
    ssrc[p] = src[i];
    sdst[p] = d;
  }
}

// All three weight preps in one launch.
// Wt layout: [n][IN] bf16 (n-major). W0: 64x128; W1: 128x128; W2|rW2: 128x(64+64).
__global__ void k_wprep_all(const float* __restrict__ W0, const float* __restrict__ W1,
                            const float* __restrict__ W2, const float* __restrict__ rW2,
                            unsigned short* __restrict__ Wt0, unsigned short* __restrict__ Wt1,
                            unsigned short* __restrict__ Wt2){
  int id = blockIdx.x*256 + threadIdx.x;
  if (id < 128*64){
    int n = id/64, k = id%64;
    Wt0[n*64 + k] = f2bf(W0[k*128 + n]);
  } else if (id < 128*64 + 128*128){
    int i = id - 128*64; int n = i/128, k = i%128;
    Wt1[n*128 + k] = f2bf(W1[k*128 + n]);
  } else if (id < 128*64 + 2*128*128){
    int i = id - 128*64 - 128*128; int n = i/128, k = i%128;
    float v = (n < 64) ? W2[k*64 + n] : rW2[k*64 + (n - 64)];
    Wt2[n*128 + k] = f2bf(v);
  }
}

// MFMA GEMM: fhb[N][128](f16 row-major) = A[N][IN] @ W(128 cols via Wt).
// A source: hb bf16 (EMBED=false) or emb[feat[n]]*fv[n] converted on the fly
// (EMBED=true, IN==64). Block 256 thr = 4 waves; wave: 16 rows x 128 cols.
// Layouts (verified): A[m=lane&15][k=quad*8+j]; B[k=quad*8+j][n=lane&15];
// D: col=lane&15, row=quad*4+reg. el/er fused (16-lane butterfly per quad).
template<int IN, int H, bool EMBED>
__global__ __launch_bounds__(256) void k_gemm_mfma(
    const unsigned short* __restrict__ hb,   // [N][IN] bf16 (unused if EMBED)
    const int* __restrict__ feat, const float* __restrict__ fv,
    const float* __restrict__ embp,          // [VOCAB][64] f32
    const unsigned short* __restrict__ Wt,   // [128][IN] bf16, n-major
    const float* __restrict__ al, const float* __restrict__ ar,
    unsigned short* __restrict__ fhb,        // [N][128] f16
    float* __restrict__ elr, int N){
  constexpr int KS = IN/32;
  constexpr int LDP = IN + 8;                // +8 bf16 pad: 2-way banks only
  __shared__ unsigned short Wt_s[128*LDP];
  const int t = threadIdx.x;
  const int lane = t & 63, wid = t >> 6;
  const int l15 = lane & 15, quad = lane >> 4;
  const int row0 = blockIdx.x*64 + wid*16;

  // stage Wt -> LDS (uint4 = 8 bf16)
  for (int id = t; id < 128*(IN/8); id += 256){
    int r = id/(IN/8), seg = id%(IN/8);
    ((uint4*)(Wt_s + r*LDP))[seg] = ((const uint4*)(Wt + (size_t)r*IN))[seg];
  }
  // A fragments from global (overlaps LDS staging)
  short8 a[KS];
  int arow = row0 + l15;
  if (EMBED){
    if (arow < N){
      const float* er2 = embp + (size_t)feat[arow]*64;
      float sc = fv[arow];
      #pragma unroll
      for (int s = 0; s < KS; s++){
        const float4* p = (const float4*)(er2 + s*32 + quad*8);
        float4 v0 = p[0], v1 = p[1];
        short8 ta;
        ta[0] = (short)f2bf(v0.x*sc); ta[1] = (short)f2bf(v0.y*sc);
        ta[2] = (short)f2bf(v0.z*sc); ta[3] = (short)f2bf(v0.w*sc);
        ta[4] = (short)f2bf(v1.x*sc); ta[5] = (short)f2bf(v1.y*sc);
        ta[6] = (short)f2bf(v1.z*sc); ta[7] = (short)f2bf(v1.w*sc);
        a[s] = ta;
      }
    } else {
      #pragma unroll
      for (int s = 0; s < KS; s++) a[s] = short8{0,0,0,0,0,0,0,0};
    }
  } else {
    #pragma unroll
    for (int s = 0; s < KS; s++){
      if (arow < N) a[s] = *(const short8*)(hb + (size_t)arow*IN + s*32 + quad*8);
      else          a[s] = short8{0,0,0,0,0,0,0,0};
    }
  }
  __syncthreads();

  float4v acc[8];
  #pragma unroll
  for (int nt = 0; nt < 8; nt++) acc[nt] = float4v{0.f,0.f,0.f,0.f};
  #pragma unroll
  for (int nt = 0; nt < 8; nt++){
    #pragma unroll
    for (int s = 0; s < KS; s++){
      short8 b = *(const short8*)(Wt_s + (nt*16 + l15)*LDP + s*32 + quad*8);
      acc[nt] = __builtin_amdgcn_mfma_f32_16x16x32_bf16(a[s], b, acc[nt], 0, 0, 0);
    }
  }

  // al/ar at this lane's columns (col = nt*16 + l15); H==1: heads>0 are zero
  float alc[8], arc[8];
  #pragma unroll
  for (int nt = 0; nt < 8; nt++){
    bool hv = (H == 2) || (nt < 4);
    alc[nt] = hv ? al[nt*16 + l15] : 0.f;
    arc[nt] = hv ? ar[nt*16 + l15] : 0.f;
  }
  #pragma unroll
  for (int reg = 0; reg < 4; reg++){
    int row = row0 + quad*4 + reg;
    bool rv = row < N;
    if (rv){
      #pragma unroll
      for (int nt = 0; nt < 8; nt++)
        fhb[(size_t)row*128 + nt*16 + l15] = f2h(acc[nt][reg]);
    }
    float pel0 = 0.f, per0 = 0.f, pel1 = 0.f, per1 = 0.f;
    #pragma unroll
    for (int nt = 0; nt < 4; nt++){
      pel0 += acc[nt][reg]*alc[nt];     per0 += acc[nt][reg]*arc[nt];
      pel1 += acc[nt+4][reg]*alc[nt+4]; per1 += acc[nt+4][reg]*arc[nt+4];
    }
    #pragma unroll
    for (int off = 1; off < 16; off <<= 1){   // reduce across the 16 lanes of a quad
      pel0 += __shfl_xor(pel0, off, 64);
      pel1 += __shfl_xor(pel1, off, 64);
      per0 += __shfl_xor(per0, off, 64);
      per1 += __shfl_xor(per1, off, 64);
    }
    if (l15 == 0 && rv){
      elr[row*4+0] = pel0;
      elr[row*4+1] = (H == 2) ? pel1 : 0.f;
      elr[row*4+2] = per0;
      elr[row*4+3] = (H == 2) ? per1 : 0.f;
    }
  }
}

// Edge-major aggregation with LDS segmented reduction. Block owns NB=64
// consecutive nodes; its CSR edge range is contiguous. 16 lane-groups stream
// contiguous sub-ranges (~64 edges each = deep loop for latency hiding).
// dst-sorted runs accumulate alpha*F in registers; flush to LDS acc via
// atomicAdd(shared f32) only on dst change. alpha computed inline from elr
// (L2-resident). Finalize after one barrier: normalize+bias+res+act+store.
template<int H>
__global__ __launch_bounds__(256) void k_agg_em(
    const unsigned short* __restrict__ fhb,  // [N][128] f16
    const float* __restrict__ elr,           // [N][4]
    const int* __restrict__ row_ptr, const int* __restrict__ ssrc,
    const int* __restrict__ sdst,
    const float* __restrict__ bias, const float* __restrict__ res,
    int act, int res_from_fh,
    float* __restrict__ out, int out_ld, unsigned* __restrict__ outb, int N){
  constexpr int NB = 64;                     // nodes per block
  constexpr int NC = (H == 2) ? 128 : 64;    // accumulated cols
  constexpr int PC = (H == 2) ? 8 : 4;       // cols per lane (16-lane group)
  __shared__ float acc_s[NB*NC];
  __shared__ float den_s[NB*2];
  const int t = threadIdx.x;
  const int n0 = blockIdx.x*NB;
  const int ncnt = min(NB, N - n0);

  for (int i = t; i < NB*NC; i += 256) acc_s[i] = 0.f;
  if (t < NB*2) den_s[t] = 0.f;
  __syncthreads();

  const int ebeg = row_ptr[n0];
  const int eend = row_ptr[n0 + ncnt];
  const int gq = t >> 4, c = t & 15;         // 16 groups x 16 lanes
  const int chunk = (eend - ebeg + 15) >> 4;
  const int gb = ebeg + gq*chunk;
  const int ge = min(gb + chunk, eend);

  const char* fhbB = (const char*)fhb;       // row = 256 B
  const unsigned cb = (H == 2) ? ((unsigned)c << 4) : ((unsigned)c << 3);

  float racc[PC];
  #pragma unroll
  for (int k = 0; k < PC; k++) racc[k] = 0.f;
  float rden0 = 0.f, rden1 = 0.f;
  int dcur = -1; float er0 = 0.f, er1 = 0.f;

  for (int i = gb; i < ge; i++){
    int s = ssrc[i], d = sdst[i];            // group-broadcast loads
    if (d != dcur){
      if (dcur >= 0){                        // flush run
        float* ap = acc_s + (dcur - n0)*NC + c*PC;
        #pragma unroll
        for (int k = 0; k < PC; k++){ atomicAdd(&ap[k], racc[k]); racc[k] = 0.f; }
        if (c == 0) atomicAdd(&den_s[(dcur - n0)*2 + 0], rden0);
        if (H == 2 && c == 1) atomicAdd(&den_s[(dcur - n0)*2 + 1], rden1);
        rden0 = 0.f; rden1 = 0.f;
      }
      dcur = d;
      if (H == 2){
        float2 er = *(const float2*)(elr + d*4 + 2); er0 = er.x; er1 = er.y;
      } else er0 = elr[d*4 + 2];
    }
    float e0, e1 = 0.f;
    if (H == 2){
      float2 el = *(const float2*)(elr + s*4);
      e0 = __expf(fminf(lrelu(el.x + er0), 30.f));
      e1 = __expf(fminf(lrelu(el.y + er1), 30.f));
    } else {
      e0 = __expf(fminf(lrelu(elr[s*4] + er0), 30.f));
    }
    rden0 += e0; rden1 += e1;
    if (H == 2){
      uint4 w = *(const uint4*)(fhbB + (((unsigned)s << 8) + cb));
      float a = (c < 8) ? e0 : e1;           // head = col/64
      const __half2* hp = (const __half2*)&w;
      #pragma unroll
      for (int q = 0; q < 4; q++){
        racc[2*q]   = fmaf((float)hp[q].x, a, racc[2*q]);
        racc[2*q+1] = fmaf((float)hp[q].y, a, racc[2*q+1]);
      }
    } else {
      uint2 w = *(const uint2*)(fhbB + (((unsigned)s << 8) + cb));
      const __half2* hp = (const __half2*)&w;
      #pragma unroll
      for (int q = 0; q < 2; q++){
        racc[2*q]   = fmaf((float)hp[q].x, e0, racc[2*q]);
        racc[2*q+1] = fmaf((float)hp[q].y, e0, racc[2*q+1]);
      }
    }
  }
  if (dcur >= 0){                            // final flush
    float* ap = acc_s + (dcur - n0)*NC + c*PC;
    #pragma unroll
    for (int k = 0; k < PC; k++) atomicAdd(&ap[k], racc[k]);
    if (c == 0) atomicAdd(&den_s[(dcur - n0)*2 + 0], rden0);
    if (H == 2 && c == 1) atomicAdd(&den_s[(dcur - n0)*2 + 1], rden1);
  }
  __syncthreads();

  // finalize: each thread handles 4 cols of one node per step
  for (int idx = t; idx < ncnt*(NC/4); idx += 256){
    int ld = idx/(NC/4), p = idx%(NC/4);
    int n = n0 + ld, col0 = p*4;
    float dn0 = den_s[ld*2], dn1 = den_s[ld*2+1];
    float rs;
    if (H == 2) rs = (col0 < 64) ? (dn0 > 0.f ? 1.f/dn0 : 0.f)
                                 : (dn1 > 0.f ? 1.f/dn1 : 0.f);
    else        rs = dn0 > 0.f ? 1.f/dn0 : 0.f;
    float o[4];
    #pragma unroll
    for (int q = 0; q < 4; q++) o[q] = fmaf(acc_s[ld*NC + col0 + q], rs, bias[col0 + q]);
    if (H == 2 && res){
      float4 rv = *(const float4*)(res + (size_t)n*128 + col0);
      o[0] += rv.x; o[1] += rv.y; o[2] += rv.z; o[3] += rv.w;
    }
    if (H == 1 && res_from_fh){
      uint2 r = *(const uint2*)(fhbB + (size_t)n*256 + 128 + col0*2);
      const __half2* rp = (const __half2*)&r;
      o[0] += (float)rp[0].x; o[1] += (float)rp[0].y;
      o[2] += (float)rp[1].x; o[3] += (float)rp[1].y;
    }
    if (act){
      #pragma unroll
      for (int q = 0; q < 4; q++) o[q] = elu1(o[q]);
    }
    if (out) *(float4*)(out + (size_t)n*out_ld + col0) =
        make_float4(o[0], o[1], o[2], o[3]);
    if (outb){
      uint2 ob;
      ob.x = (unsigned)f2bf(o[0]) | ((unsigned)f2bf(o[1]) << 16);
      ob.y = (unsigned)f2bf(o[2]) | ((unsigned)f2bf(o[3]) << 16);
      *(uint2*)(outb + (size_t)n*64 + (col0 >> 1)) = ob;
    }
  }
}

extern "C" void kernel_launch(void* const* d_in, const int* in_sizes, int n_in,
                              void* d_out, int out_size, void* d_ws, size_t ws_size,
                              hipStream_t stream) {
  const int*   feat = (const int*)  d_in[0];
  const float* fv   = (const float*)d_in[1];
  const int*   src  = (const int*)  d_in[2];
  const int*   dst  = (const int*)  d_in[3];
  const float* emb  = (const float*)d_in[4];
  const float* W0   = (const float*)d_in[5];
  const float* al0  = (const float*)d_in[6];
  const float* ar0  = (const float*)d_in[7];
  const float* b0   = (const float*)d_in[8];
  const float* W1   = (const float*)d_in[9];
  const float* al1  = (const float*)d_in[10];
  const float* ar1  = (const float*)d_in[11];
  const float* b1   = (const float*)d_in[12];
  const float* W2   = (const float*)d_in[13];
  const float* al2  = (const float*)d_in[14];
  const float* ar2  = (const float*)d_in[15];
  const float* b2   = (const float*)d_in[16];
  const float* rW2  = (const float*)d_in[17];
  const int N = in_sizes[0] / 8;   // 50000
  const int E = in_sizes[2];       // 800000

  size_t off = 0;
  auto alloc = [&](size_t bytes) -> void* {
    void* p = (char*)d_ws + off;
    off = (off + bytes + 255) & ~(size_t)255;
    return p;
  };
  unsigned short* P1 = (unsigned short*)alloc((size_t)N*128*sizeof(unsigned short)); // fhb f16
  float* P2     = (float*)alloc((size_t)N*128*sizeof(float));                        // layer0 out (res for layer1)
  unsigned short* hb = (unsigned short*)alloc((size_t)N*128*sizeof(unsigned short)); // h bf16
  float* elr    = (float*)alloc((size_t)N*4*sizeof(float));
  int* row_ptr  = (int*)alloc((size_t)(N+1)*sizeof(int));
  int* counts   = (int*)alloc((size_t)N*sizeof(int));
  int* rank     = (int*)alloc((size_t)E*sizeof(int));
  int* ssrc     = (int*)alloc((size_t)E*sizeof(int));
  int* sdst     = (int*)alloc((size_t)E*sizeof(int));
  int* bsum     = (int*)alloc(256*sizeof(int));
  unsigned short* Wt0 = (unsigned short*)alloc((size_t)128*64*sizeof(unsigned short));
  unsigned short* Wt1 = (unsigned short*)alloc((size_t)128*128*sizeof(unsigned short));
  unsigned short* Wt2 = (unsigned short*)alloc((size_t)128*128*sizeof(unsigned short));

  int nb1 = (N + 255) / 256;
  int eb  = (E + 255) / 256;
  // CSR build (rank captured in hist atomic; scatter atomic-free)
  k_zero_i32<<<(N + 255)/256, 256, 0, stream>>>(counts, N);
  k_hist_rank<<<eb, 256, 0, stream>>>(dst, counts, rank, E);
  k_scan_local<<<nb1, 256, 0, stream>>>(counts, row_ptr, bsum, N);
  k_scan_top<<<1, 256, 0, stream>>>(bsum, nb1);
  k_scan_fix<<<nb1, 256, 0, stream>>>(row_ptr, bsum, N);
  k_scatter2<<<eb, 256, 0, stream>>>(src, dst, rank, row_ptr, ssrc, sdst, E);
  // weight transpose+bf16 prep (single launch)
  k_wprep_all<<<(128*64 + 2*128*128 + 255)/256, 256, 0, stream>>>(
      W0, W1, W2, rW2, Wt0, Wt1, Wt2);

  int gt  = (N + 63)/64;
  int nem = (N + 63)/64;
  // layer 0: in=64, H=2, embed fused into A-load, no residual, elu
  k_gemm_mfma<64,2,true><<<gt, 256, 0, stream>>>(nullptr, feat, fv, emb,
                                                 Wt0, al0, ar0, P1, elr, N);
  k_agg_em<2><<<nem, 256, 0, stream>>>(P1, elr, row_ptr, ssrc, sdst, b0, nullptr,
                                       1, 0, P2, 128, (unsigned*)hb, N);
  // layer 1: in=128, H=2, identity residual, elu; float out unused -> skip store
  k_gemm_mfma<128,2,false><<<gt, 256, 0, stream>>>(hb, nullptr, nullptr, nullptr,
                                                   Wt1, al1, ar1, P1, elr, N);
  k_agg_em<2><<<nem, 256, 0, stream>>>(P1, elr, row_ptr, ssrc, sdst, b1, P2,
                                       1, 0, nullptr, 128, (unsigned*)hb, N);
  // layer 2: in=128, H=1, projected residual (fh cols 64..127 = h@resW2), no act
  k_gemm_mfma<128,1,false><<<gt, 256, 0, stream>>>(hb, nullptr, nullptr, nullptr,
                                                   Wt2, al2, ar2, P1, elr, N);
  k_agg_em<1><<<nem, 256, 0, stream>>>(P1, elr, row_ptr, ssrc, sdst, b2, nullptr,
                                       0, 1, (float*)d_out, 64, nullptr, N);
}

// Round 8
// 322.024 us; speedup vs baseline: 1.3674x; 1.3674x over previous
//
#include <hip/hip_runtime.h>
#include <hip/hip_fp16.h>

// GAT (3-layer) on MI355X. N=50000 nodes, E=800000 edges, D=64, H=2/2/1.
// R14: R13 edge-major reverted (83us, LDS-occ + branch serialization).
//      k_agg rewritten GROUP-PER-NODE: wave = 4 nodes, one 16-lane group owns
//      each node and streams its edges serially (lane c = 16B of the row).
//      alpha computed inline per edge (redundant across the group's 16 lanes;
//      4 groups share the wave instruction). den accumulates identically in
//      all group lanes -> ZERO cross-lane ops: no den butterfly, no acc
//      combine, no alpha-window packing, all 64 lanes active in epilogue.
//      2x unroll = 6 independent VMEM per step. 12500 waves (was 50000),
//      VGPR ~36, no LDS. k_zero+k_wprep fused into k_setup; sdst deleted.

typedef __attribute__((ext_vector_type(8))) short short8;   // 8 bf16 (4 VGPRs)
typedef __attribute__((ext_vector_type(4))) float float4v;  // 4 fp32 acc

__device__ __forceinline__ float lrelu(float x){ return fmaxf(x, 0.2f*x); }

__device__ __forceinline__ unsigned short f2bf(float f){   // RNE round
  unsigned int u = __float_as_uint(f);
  u += 0x7fffu + ((u >> 16) & 1u);
  return (unsigned short)(u >> 16);
}
__device__ __forceinline__ unsigned short f2h(float f){
  return __half_as_ushort(__float2half(f));
}
__device__ __forceinline__ float elu1(float x){            // elu, x<0 branch via exp
  return x > 0.f ? x : (__expf(x) - 1.f);
}

// hist + rank in one atomic: rank[i] = position of edge i within its dst bucket
__global__ void k_hist_rank(const int* __restrict__ dst, int* __restrict__ counts,
                            int* __restrict__ rank, int E){
  int i = blockIdx.x*blockDim.x + threadIdx.x;
  if (i < E){
    int d = dst[i];
    rank[i] = atomicAdd(&counts[d], 1);
  }
}

__global__ void k_scan_local(const int* __restrict__ counts, int* __restrict__ row_ptr,
                             int* __restrict__ bsum, int N){
  __shared__ int s[256];
  int t = threadIdx.x, g = blockIdx.x*256 + t;
  int v = (g < N) ? counts[g] : 0;
  s[t] = v; __syncthreads();
  #pragma unroll
  for (int off = 1; off < 256; off <<= 1){
    int x = 0;
    if (t >= off) x = s[t-off];
    __syncthreads();
    s[t] += x;
    __syncthreads();
  }
  if (g < N) row_ptr[g+1] = s[t];
  if (g == 0 && t == 0) row_ptr[0] = 0;
  if (t == 255) bsum[blockIdx.x] = s[255];
}

__global__ void k_scan_top(int* __restrict__ bsum, int nb){
  __shared__ int s[256];
  int t = threadIdx.x;
  int v = (t < nb) ? bsum[t] : 0;
  s[t] = v; __syncthreads();
  #pragma unroll
  for (int off = 1; off < 256; off <<= 1){
    int x = 0;
    if (t >= off) x = s[t-off];
    __syncthreads();
    s[t] += x;
    __syncthreads();
  }
  if (t < nb) bsum[t] = s[t] - v;  // exclusive block offsets
}

__global__ void k_scan_fix(int* __restrict__ row_ptr, const int* __restrict__ bsum, int N){
  int g = blockIdx.x*256 + threadIdx.x;
  if (g < N && blockIdx.x > 0) row_ptr[g+1] += bsum[blockIdx.x];
}

// atomic-free scatter: pos comes from rank captured during hist
__global__ void k_scatter2(const int* __restrict__ src, const int* __restrict__ dst,
                           const int* __restrict__ rank, const int* __restrict__ row_ptr,
                           int* __restrict__ ssrc, int E){
  int i = blockIdx.x*blockDim.x + threadIdx.x;
  if (i < E) ssrc[row_ptr[dst[i]] + rank[i]] = src[i];
}

// Fused setup: zero counts + all three weight preps (independent elementwise).
// Wt layout: [n][IN] bf16 (n-major). W0: 64x128; W1: 128x128; W2|rW2: 128x(64+64).
__global__ void k_setup(int* __restrict__ counts, int N,
                        const float* __restrict__ W0, const float* __restrict__ W1,
                        const float* __restrict__ W2, const float* __restrict__ rW2,
                        unsigned short* __restrict__ Wt0, unsigned short* __restrict__ Wt1,
                        unsigned short* __restrict__ Wt2){
  int id = blockIdx.x*256 + threadIdx.x;
  if (id < N){ counts[id] = 0; return; }
  int j = id - N;
  if (j < 128*64){
    int n = j/64, k = j%64;
    Wt0[n*64 + k] = f2bf(W0[k*128 + n]);
  } else if (j < 128*64 + 128*128){
    int i = j - 128*64; int n = i/128, k = i%128;
    Wt1[n*128 + k] = f2bf(W1[k*128 + n]);
  } else if (j < 128*64 + 2*128*128){
    int i = j - 128*64 - 128*128; int n = i/128, k = i%128;
    float v = (n < 64) ? W2[k*64 + n] : rW2[k*64 + (n - 64)];
    Wt2[n*128 + k] = f2bf(v);
  }
}

// MFMA GEMM: fhb[N][128](f16 row-major) = A[N][IN] @ W(128 cols via Wt).
// A source: hb bf16 (EMBED=false) or emb[feat[n]]*fv[n] converted on the fly
// (EMBED=true, IN==64). Block 256 thr = 4 waves; wave: 16 rows x 128 cols.
// Layouts (verified): A[m=lane&15][k=quad*8+j]; B[k=quad*8+j][n=lane&15];
// D: col=lane&15, row=quad*4+reg. el/er fused (16-lane butterfly per quad).
template<int IN, int H, bool EMBED>
__global__ __launch_bounds__(256) void k_gemm_mfma(
    const unsigned short* __restrict__ hb,   // [N][IN] bf16 (unused if EMBED)
    const int* __restrict__ feat, const float* __restrict__ fv,
    const float* __restrict__ embp,          // [VOCAB][64] f32
    const unsigned short* __restrict__ Wt,   // [128][IN] bf16, n-major
    const float* __restrict__ al, const float* __restrict__ ar,
    unsigned short* __restrict__ fhb,        // [N][128] f16
    float* __restrict__ elr, int N){
  constexpr int KS = IN/32;
  constexpr int LDP = IN + 8;                // +8 bf16 pad: 2-way banks only
  __shared__ unsigned short Wt_s[128*LDP];
  const int t = threadIdx.x;
  const int lane = t & 63, wid = t >> 6;
  const int l15 = lane & 15, quad = lane >> 4;
  const int row0 = blockIdx.x*64 + wid*16;

  // stage Wt -> LDS (uint4 = 8 bf16)
  for (int id = t; id < 128*(IN/8); id += 256){
    int r = id/(IN/8), seg = id%(IN/8);
    ((uint4*)(Wt_s + r*LDP))[seg] = ((const uint4*)(Wt + (size_t)r*IN))[seg];
  }
  // A fragments from global (overlaps LDS staging)
  short8 a[KS];
  int arow = row0 + l15;
  if (EMBED){
    if (arow < N){
      const float* er2 = embp + (size_t)feat[arow]*64;
      float sc = fv[arow];
      #pragma unroll
      for (int s = 0; s < KS; s++){
        const float4* p = (const float4*)(er2 + s*32 + quad*8);
        float4 v0 = p[0], v1 = p[1];
        short8 ta;
        ta[0] = (short)f2bf(v0.x*sc); ta[1] = (short)f2bf(v0.y*sc);
        ta[2] = (short)f2bf(v0.z*sc); ta[3] = (short)f2bf(v0.w*sc);
        ta[4] = (short)f2bf(v1.x*sc); ta[5] = (short)f2bf(v1.y*sc);
        ta[6] = (short)f2bf(v1.z*sc); ta[7] = (short)f2bf(v1.w*sc);
        a[s] = ta;
      }
    } else {
      #pragma unroll
      for (int s = 0; s < KS; s++) a[s] = short8{0,0,0,0,0,0,0,0};
    }
  } else {
    #pragma unroll
    for (int s = 0; s < KS; s++){
      if (arow < N) a[s] = *(const short8*)(hb + (size_t)arow*IN + s*32 + quad*8);
      else          a[s] = short8{0,0,0,0,0,0,0,0};
    }
  }
  __syncthreads();

  float4v acc[8];
  #pragma unroll
  for (int nt = 0; nt < 8; nt++) acc[nt] = float4v{0.f,0.f,0.f,0.f};
  #pragma unroll
  for (int nt = 0; nt < 8; nt++){
    #pragma unroll
    for (int s = 0; s < KS; s++){
      short8 b = *(const short8*)(Wt_s + (nt*16 + l15)*LDP + s*32 + quad*8);
      acc[nt] = __builtin_amdgcn_mfma_f32_16x16x32_bf16(a[s], b, acc[nt], 0, 0, 0);
    }
  }

  // al/ar at this lane's columns (col = nt*16 + l15); H==1: heads>0 are zero
  float alc[8], arc[8];
  #pragma unroll
  for (int nt = 0; nt < 8; nt++){
    bool hv = (H == 2) || (nt < 4);
    alc[nt] = hv ? al[nt*16 + l15] : 0.f;
    arc[nt] = hv ? ar[nt*16 + l15] : 0.f;
  }
  #pragma unroll
  for (int reg = 0; reg < 4; reg++){
    int row = row0 + quad*4 + reg;
    bool rv = row < N;
    if (rv){
      #pragma unroll
      for (int nt = 0; nt < 8; nt++)
        fhb[(size_t)row*128 + nt*16 + l15] = f2h(acc[nt][reg]);
    }
    float pel0 = 0.f, per0 = 0.f, pel1 = 0.f, per1 = 0.f;
    #pragma unroll
    for (int nt = 0; nt < 4; nt++){
      pel0 += acc[nt][reg]*alc[nt];     per0 += acc[nt][reg]*arc[nt];
      pel1 += acc[nt+4][reg]*alc[nt+4]; per1 += acc[nt+4][reg]*arc[nt+4];
    }
    #pragma unroll
    for (int off = 1; off < 16; off <<= 1){   // reduce across the 16 lanes of a quad
      pel0 += __shfl_xor(pel0, off, 64);
      pel1 += __shfl_xor(pel1, off, 64);
      per0 += __shfl_xor(per0, off, 64);
      per1 += __shfl_xor(per1, off, 64);
    }
    if (l15 == 0 && rv){
      elr[row*4+0] = pel0;
      elr[row*4+1] = (H == 2) ? pel1 : 0.f;
      elr[row*4+2] = per0;
      elr[row*4+3] = (H == 2) ? per1 : 0.f;
    }
  }
}

// GROUP-PER-NODE aggregation: block = 256 thr = 16 groups of 16 lanes; each
// group owns ONE node and streams its edges serially. Lane c holds a 16B (H=2,
// full 256B row) / 8B (H=1, cols 0..63) chunk. alpha computed inline per edge
// (same value in all 16 lanes of the group — no cross-lane ops anywhere).
// den accumulates identically per lane -> epilogue reciprocal needs no reduce.
// 2x unroll: 6 independent VMEM per step. Single pass (normalize at the end).
template<int H>
__global__ __launch_bounds__(256) void k_agg_gp(
    const unsigned short* __restrict__ fhb,  // [N][128] f16
    const float* __restrict__ elr,           // [N][4]
    const int* __restrict__ row_ptr, const int* __restrict__ ssrc,
    const float* __restrict__ bias, const float* __restrict__ res,
    int act, int res_from_fh,
    float* __restrict__ out, int out_ld, unsigned* __restrict__ outb, int N){
  const int t = threadIdx.x;
  const int gq = t >> 4, c = t & 15;         // group, lane-in-group
  const int n = blockIdx.x*16 + gq;
  if (n >= N) return;
  const int beg = row_ptr[n], end = row_ptr[n+1];
  const float er0 = elr[n*4+2];
  const float er1 = (H == 2) ? elr[n*4+3] : 0.f;

  const char* fhbB = (const char*)fhb;       // row = 256 B, 32-bit offsets
  const unsigned cb = (H == 2) ? ((unsigned)c << 4) : ((unsigned)c << 3);
  constexpr int PC = (H == 2) ? 8 : 4;       // cols per lane

  float acc[PC];
  #pragma unroll
  for (int k = 0; k < PC; k++) acc[k] = 0.f;
  float den0 = 0.f, den1 = 0.f;

  int i = beg;
  for (; i + 1 < end; i += 2){               // 2-deep: 6 independent VMEM
    int s0 = ssrc[i], s1 = ssrc[i+1];
    float2 el0 = *(const float2*)(elr + s0*4);
    float2 el1 = *(const float2*)(elr + s1*4);
    float e00 = __expf(fminf(lrelu(el0.x + er0), 30.f));
    float e10 = __expf(fminf(lrelu(el1.x + er0), 30.f));
    float e01 = 0.f, e11 = 0.f;
    if (H == 2){
      e01 = __expf(fminf(lrelu(el0.y + er1), 30.f));
      e11 = __expf(fminf(lrelu(el1.y + er1), 30.f));
    }
    den0 += e00 + e10; den1 += e01 + e11;
    if (H == 2){
      uint4 w0 = *(const uint4*)(fhbB + (((unsigned)s0 << 8) + cb));
      uint4 w1 = *(const uint4*)(fhbB + (((unsigned)s1 << 8) + cb));
      float a0 = (c < 8) ? e00 : e01;        // head = col/64
      float a1 = (c < 8) ? e10 : e11;
      const __half2* h0 = (const __half2*)&w0;
      const __half2* h1 = (const __half2*)&w1;
      #pragma unroll
      for (int q = 0; q < 4; q++){
        acc[2*q]   = fmaf((float)h0[q].x, a0, acc[2*q]);
        acc[2*q+1] = fmaf((float)h0[q].y, a0, acc[2*q+1]);
      }
      #pragma unroll
      for (int q = 0; q < 4; q++){
        acc[2*q]   = fmaf((float)h1[q].x, a1, acc[2*q]);
        acc[2*q+1] = fmaf((float)h1[q].y, a1, acc[2*q+1]);
      }
    } else {
      uint2 w0 = *(const uint2*)(fhbB + (((unsigned)s0 << 8) + cb));
      uint2 w1 = *(const uint2*)(fhbB + (((unsigned)s1 << 8) + cb));
      const __half2* h0 = (const __half2*)&w0;
      const __half2* h1 = (const __half2*)&w1;
      #pragma unroll
      for (int q = 0; q < 2; q++){
        acc[2*q]   = fmaf((float)h0[q].x, e00, acc[2*q]);
        acc[2*q+1] = fmaf((float)h0[q].y, e00, acc[2*q+1]);
      }
      #pragma unroll
      for (int q = 0; q < 2; q++){
        acc[2*q]   = fmaf((float)h1[q].x, e10, acc[2*q]);
        acc[2*q+1] = fmaf((float)h1[q].y, e10, acc[2*q+1]);
      }
    }
  }
  if (i < end){                              // tail edge
    int s0 = ssrc[i];
    float2 el0 = *(const float2*)(elr + s0*4);
    float e00 = __expf(fminf(lrelu(el0.x + er0), 30.f));
    float e01 = (H == 2) ? __expf(fminf(lrelu(el0.y + er1), 30.f)) : 0.f;
    den0 += e00; den1 += e01;
    if (H == 2){
      uint4 w0 = *(const uint4*)(fhbB + (((unsigned)s0 << 8) + cb));
      float a0 = (c < 8) ? e00 : e01;
      const __half2* h0 = (const __half2*)&w0;
      #pragma unroll
      for (int q = 0; q < 4; q++){
        acc[2*q]   = fmaf((float)h0[q].x, a0, acc[2*q]);
        acc[2*q+1] = fmaf((float)h0[q].y, a0, acc[2*q+1]);
      }
    } else {
      uint2 w0 = *(const uint2*)(fhbB + (((unsigned)s0 << 8) + cb));
      const __half2* h0 = (const __half2*)&w0;
      #pragma unroll
      for (int q = 0; q < 2; q++){
        acc[2*q]   = fmaf((float)h0[q].x, e00, acc[2*q]);
        acc[2*q+1] = fmaf((float)h0[q].y, e00, acc[2*q+1]);
      }
    }
  }

  // epilogue: den identical across the group's lanes — no reduce needed.
  float rd0 = den0 > 0.f ? 1.f/den0 : 0.f;
  float rd1 = (H == 2 && den1 > 0.f) ? 1.f/den1 : 0.f;

  if (H == 2){
    float rs = (c < 8) ? rd0 : rd1;
    float o[8];
    const float4* b4 = (const float4*)(bias + c*8);
    float4 ba = b4[0], bb = b4[1];
    o[0]=fmaf(acc[0],rs,ba.x); o[1]=fmaf(acc[1],rs,ba.y);
    o[2]=fmaf(acc[2],rs,ba.z); o[3]=fmaf(acc[3],rs,ba.w);
    o[4]=fmaf(acc[4],rs,bb.x); o[5]=fmaf(acc[5],rs,bb.y);
    o[6]=fmaf(acc[6],rs,bb.z); o[7]=fmaf(acc[7],rs,bb.w);
    if (res){
      const float4* r4 = (const float4*)(res + (size_t)n*128 + c*8);
      float4 ra = r4[0], rb = r4[1];
      o[0]+=ra.x; o[1]+=ra.y; o[2]+=ra.z; o[3]+=ra.w;
      o[4]+=rb.x; o[5]+=rb.y; o[6]+=rb.z; o[7]+=rb.w;
    }
    if (act){
      #pragma unroll
      for (int k = 0; k < 8; k++) o[k] = elu1(o[k]);
    }
    if (out){
      float4* o4 = (float4*)(out + (size_t)n*out_ld + c*8);
      o4[0] = make_float4(o[0], o[1], o[2], o[3]);
      o4[1] = make_float4(o[4], o[5], o[6], o[7]);
    }
    if (outb){
      uint4 ob;
      ob.x = (unsigned)f2bf(o[0]) | ((unsigned)f2bf(o[1]) << 16);
      ob.y = (unsigned)f2bf(o[2]) | ((unsigned)f2bf(o[3]) << 16);
      ob.z = (unsigned)f2bf(o[4]) | ((unsigned)f2bf(o[5]) << 16);
      ob.w = (unsigned)f2bf(o[6]) | ((unsigned)f2bf(o[7]) << 16);
      *(uint4*)(outb + (size_t)n*64 + c*4) = ob;
    }
  } else {
    float o[4];
    #pragma unroll
    for (int k = 0; k < 4; k++) o[k] = fmaf(acc[k], rd0, bias[c*4 + k]);
    if (res_from_fh){
      uint2 r = *(const uint2*)(fhbB + (size_t)n*256 + 128 + c*8);
      const __half2* rp = (const __half2*)&r;
      o[0] += (float)rp[0].x; o[1] += (float)rp[0].y;
      o[2] += (float)rp[1].x; o[3] += (float)rp[1].y;
    }
    if (act){
      #pragma unroll
      for (int k = 0; k < 4; k++) o[k] = elu1(o[k]);
    }
    *(float4*)(out + (size_t)n*out_ld + c*4) = make_float4(o[0], o[1], o[2], o[3]);
  }
}

extern "C" void kernel_launch(void* const* d_in, const int* in_sizes, int n_in,
                              void* d_out, int out_size, void* d_ws, size_t ws_size,
                              hipStream_t stream) {
  const int*   feat = (const int*)  d_in[0];
  const float* fv   = (const float*)d_in[1];
  const int*   src  = (const int*)  d_in[2];
  const int*   dst  = (const int*)  d_in[3];
  const float* emb  = (const float*)d_in[4];
  const float* W0   = (const float*)d_in[5];
  const float* al0  = (const float*)d_in[6];
  const float* ar0  = (const float*)d_in[7];
  const float* b0   = (const float*)d_in[8];
  const float* W1   = (const float*)d_in[9];
  const float* al1  = (const float*)d_in[10];
  const float* ar1  = (const float*)d_in[11];
  const float* b1   = (const float*)d_in[12];
  const float* W2   = (const float*)d_in[13];
  const float* al2  = (const float*)d_in[14];
  const float* ar2  = (const float*)d_in[15];
  const float* b2   = (const float*)d_in[16];
  const float* rW2  = (const float*)d_in[17];
  const int N = in_sizes[0] / 8;   // 50000
  const int E = in_sizes[2];       // 800000

  size_t off = 0;
  auto alloc = [&](size_t bytes) -> void* {
    void* p = (char*)d_ws + off;
    off = (off + bytes + 255) & ~(size_t)255;
    return p;
  };
  unsigned short* P1 = (unsigned short*)alloc((size_t)N*128*sizeof(unsigned short)); // fhb f16
  float* P2     = (float*)alloc((size_t)N*128*sizeof(float));                        // layer0 out (res for layer1)
  unsigned short* hb = (unsigned short*)alloc((size_t)N*128*sizeof(unsigned short)); // h bf16
  float* elr    = (float*)alloc((size_t)N*4*sizeof(float));
  int* row_ptr  = (int*)alloc((size_t)(N+1)*sizeof(int));
  int* counts   = (int*)alloc((size_t)N*sizeof(int));
  int* rank     = (int*)alloc((size_t)E*sizeof(int));
  int* ssrc     = (int*)alloc((size_t)E*sizeof(int));
  int* bsum     = (int*)alloc(256*sizeof(int));
  unsigned short* Wt0 = (unsigned short*)alloc((size_t)128*64*sizeof(unsigned short));
  unsigned short* Wt1 = (unsigned short*)alloc((size_t)128*128*sizeof(unsigned short));
  unsigned short* Wt2 = (unsigned short*)alloc((size_t)128*128*sizeof(unsigned short));

  int nb1 = (N + 255) / 256;
  int eb  = (E + 255) / 256;
  // setup: zero counts + weight preps (one launch)
  k_setup<<<(N + 128*64 + 2*128*128 + 255)/256, 256, 0, stream>>>(
      counts, N, W0, W1, W2, rW2, Wt0, Wt1, Wt2);
  // CSR build (rank captured in hist atomic; scatter atomic-free)
  k_hist_rank<<<eb, 256, 0, stream>>>(dst, counts, rank, E);
  k_scan_local<<<nb1, 256, 0, stream>>>(counts, row_ptr, bsum, N);
  k_scan_top<<<1, 256, 0, stream>>>(bsum, nb1);
  k_scan_fix<<<nb1, 256, 0, stream>>>(row_ptr, bsum, N);
  k_scatter2<<<eb, 256, 0, stream>>>(src, dst, rank, row_ptr, ssrc, E);

  int gt  = (N + 63)/64;
  int ngp = (N + 15)/16;
  // layer 0: in=64, H=2, embed fused into A-load, no residual, elu
  k_gemm_mfma<64,2,true><<<gt, 256, 0, stream>>>(nullptr, feat, fv, emb,
                                                 Wt0, al0, ar0, P1, elr, N);
  k_agg_gp<2><<<ngp, 256, 0, stream>>>(P1, elr, row_ptr, ssrc, b0, nullptr,
                                       1, 0, P2, 128, (unsigned*)hb, N);
  // layer 1: in=128, H=2, identity residual, elu; float out unused -> skip store
  k_gemm_mfma<128,2,false><<<gt, 256, 0, stream>>>(hb, nullptr, nullptr, nullptr,
                                                   Wt1, al1, ar1, P1, elr, N);
  k_agg_gp<2><<<ngp, 256, 0, stream>>>(P1, elr, row_ptr, ssrc, b1, P2,
                                       1, 0, nullptr, 128, (unsigned*)hb, N);
  // layer 2: in=128, H=1, projected residual (fh cols 64..127 = h@resW2), no act
  k_gemm_mfma<128,1,false><<<gt, 256, 0, stream>>>(hb, nullptr, nullptr, nullptr,
                                                   Wt2, al2, ar2, P1, elr, N);
  k_agg_gp<1><<<ngp, 256, 0, stream>>>(P1, elr, row_ptr, ssrc, b2, nullptr,
                                       0, 1, (float*)d_out, 64, nullptr, N);
}

// Round 9
// 314.258 us; speedup vs baseline: 1.4012x; 1.0247x over previous
//
#include <hip/hip_runtime.h>
#include <hip/hip_fp16.h>

// GAT (3-layer) on MI355X. N=50000 nodes, E=800000 edges, D=64, H=2/2/1.
// R15 = R14 + 4-deep gather unroll in k_agg_gp (one variable). R14 counters:
//      VALU 37%, HBM 40%, occ 51% -> latency-exposed with only 2 chains in
//      flight. R14's lean structure is 24 VGPR (R10's deep-batch failure was
//      52-VGPR window state, not depth itself); 4-deep adds ~20 VGPR -> ~44,
//      under the 64 cliff. 4 independent ssrc->elr->row chains, 12 VMEM in
//      flight per step, 1-edge tail loop. Everything else identical to R14.

typedef __attribute__((ext_vector_type(8))) short short8;   // 8 bf16 (4 VGPRs)
typedef __attribute__((ext_vector_type(4))) float float4v;  // 4 fp32 acc

__device__ __forceinline__ float lrelu(float x){ return fmaxf(x, 0.2f*x); }

__device__ __forceinline__ unsigned short f2bf(float f){   // RNE round
  unsigned int u = __float_as_uint(f);
  u += 0x7fffu + ((u >> 16) & 1u);
  return (unsigned short)(u >> 16);
}
__device__ __forceinline__ unsigned short f2h(float f){
  return __half_as_ushort(__float2half(f));
}
__device__ __forceinline__ float elu1(float x){            // elu, x<0 branch via exp
  return x > 0.f ? x : (__expf(x) - 1.f);
}

// hist + rank in one atomic: rank[i] = position of edge i within its dst bucket
__global__ void k_hist_rank(const int* __restrict__ dst, int* __restrict__ counts,
                            int* __restrict__ rank, int E){
  int i = blockIdx.x*blockDim.x + threadIdx.x;
  if (i < E){
    int d = dst[i];
    rank[i] = atomicAdd(&counts[d], 1);
  }
}

__global__ void k_scan_local(const int* __restrict__ counts, int* __restrict__ row_ptr,
                             int* __restrict__ bsum, int N){
  __shared__ int s[256];
  int t = threadIdx.x, g = blockIdx.x*256 + t;
  int v = (g < N) ? counts[g] : 0;
  s[t] = v; __syncthreads();
  #pragma unroll
  for (int off = 1; off < 256; off <<= 1){
    int x = 0;
    if (t >= off) x = s[t-off];
    __syncthreads();
    s[t] += x;
    __syncthreads();
  }
  if (g < N) row_ptr[g+1] = s[t];
  if (g == 0 && t == 0) row_ptr[0] = 0;
  if (t == 255) bsum[blockIdx.x] = s[255];
}

__global__ void k_scan_top(int* __restrict__ bsum, int nb){
  __shared__ int s[256];
  int t = threadIdx.x;
  int v = (t < nb) ? bsum[t] : 0;
  s[t] = v; __syncthreads();
  #pragma unroll
  for (int off = 1; off < 256; off <<= 1){
    int x = 0;
    if (t >= off) x = s[t-off];
    __syncthreads();
    s[t] += x;
    __syncthreads();
  }
  if (t < nb) bsum[t] = s[t] - v;  // exclusive block offsets
}

__global__ void k_scan_fix(int* __restrict__ row_ptr, const int* __restrict__ bsum, int N){
  int g = blockIdx.x*256 + threadIdx.x;
  if (g < N && blockIdx.x > 0) row_ptr[g+1] += bsum[blockIdx.x];
}

// atomic-free scatter: pos comes from rank captured during hist
__global__ void k_scatter2(const int* __restrict__ src, const int* __restrict__ dst,
                           const int* __restrict__ rank, const int* __restrict__ row_ptr,
                           int* __restrict__ ssrc, int E){
  int i = blockIdx.x*blockDim.x + threadIdx.x;
  if (i < E) ssrc[row_ptr[dst[i]] + rank[i]] = src[i];
}

// Fused setup: zero counts + all three weight preps (independent elementwise).
// Wt layout: [n][IN] bf16 (n-major). W0: 64x128; W1: 128x128; W2|rW2: 128x(64+64).
__global__ void k_setup(int* __restrict__ counts, int N,
                        const float* __restrict__ W0, const float* __restrict__ W1,
                        const float* __restrict__ W2, const float* __restrict__ rW2,
                        unsigned short* __restrict__ Wt0, unsigned short* __restrict__ Wt1,
                        unsigned short* __restrict__ Wt2){
  int id = blockIdx.x*256 + threadIdx.x;
  if (id < N){ counts[id] = 0; return; }
  int j = id - N;
  if (j < 128*64){
    int n = j/64, k = j%64;
    Wt0[n*64 + k] = f2bf(W0[k*128 + n]);
  } else if (j < 128*64 + 128*128){
    int i = j - 128*64; int n = i/128, k = i%128;
    Wt1[n*128 + k] = f2bf(W1[k*128 + n]);
  } else if (j < 128*64 + 2*128*128){
    int i = j - 128*64 - 128*128; int n = i/128, k = i%128;
    float v = (n < 64) ? W2[k*64 + n] : rW2[k*64 + (n - 64)];
    Wt2[n*128 + k] = f2bf(v);
  }
}

// MFMA GEMM: fhb[N][128](f16 row-major) = A[N][IN] @ W(128 cols via Wt).
// A source: hb bf16 (EMBED=false) or emb[feat[n]]*fv[n] converted on the fly
// (EMBED=true, IN==64). Block 256 thr = 4 waves; wave: 16 rows x 128 cols.
// Layouts (verified): A[m=lane&15][k=quad*8+j]; B[k=quad*8+j][n=lane&15];
// D: col=lane&15, row=quad*4+reg. el/er fused (16-lane butterfly per quad).
template<int IN, int H, bool EMBED>
__global__ __launch_bounds__(256) void k_gemm_mfma(
    const unsigned short* __restrict__ hb,   // [N][IN] bf16 (unused if EMBED)
    const int* __restrict__ feat, const float* __restrict__ fv,
    const float* __restrict__ embp,          // [VOCAB][64] f32
    const unsigned short* __restrict__ Wt,   // [128][IN] bf16, n-major
    const float* __restrict__ al, const float* __restrict__ ar,
    unsigned short* __restrict__ fhb,        // [N][128] f16
    float* __restrict__ elr, int N){
  constexpr int KS = IN/32;
  constexpr int LDP = IN + 8;                // +8 bf16 pad: 2-way banks only
  __shared__ unsigned short Wt_s[128*LDP];
  const int t = threadIdx.x;
  const int lane = t & 63, wid = t >> 6;
  const int l15 = lane & 15, quad = lane >> 4;
  const int row0 = blockIdx.x*64 + wid*16;

  // stage Wt -> LDS (uint4 = 8 bf16)
  for (int id = t; id < 128*(IN/8); id += 256){
    int r = id/(IN/8), seg = id%(IN/8);
    ((uint4*)(Wt_s + r*LDP))[seg] = ((const uint4*)(Wt + (size_t)r*IN))[seg];
  }
  // A fragments from global (overlaps LDS staging)
  short8 a[KS];
  int arow = row0 + l15;
  if (EMBED){
    if (arow < N){
      const float* er2 = embp + (size_t)feat[arow]*64;
      float sc = fv[arow];
      #pragma unroll
      for (int s = 0; s < KS; s++){
        const float4* p = (const float4*)(er2 + s*32 + quad*8);
        float4 v0 = p[0], v1 = p[1];
        short8 ta;
        ta[0] = (short)f2bf(v0.x*sc); ta[1] = (short)f2bf(v0.y*sc);
        ta[2] = (short)f2bf(v0.z*sc); ta[3] = (short)f2bf(v0.w*sc);
        ta[4] = (short)f2bf(v1.x*sc); ta[5] = (short)f2bf(v1.y*sc);
        ta[6] = (short)f2bf(v1.z*sc); ta[7] = (short)f2bf(v1.w*sc);
        a[s] = ta;
      }
    } else {
      #pragma unroll
      for (int s = 0; s < KS; s++) a[s] = short8{0,0,0,0,0,0,0,0};
    }
  } else {
    #pragma unroll
    for (int s = 0; s < KS; s++){
      if (arow < N) a[s] = *(const short8*)(hb + (size_t)arow*IN + s*32 + quad*8);
      else          a[s] = short8{0,0,0,0,0,0,0,0};
    }
  }
  __syncthreads();

  float4v acc[8];
  #pragma unroll
  for (int nt = 0; nt < 8; nt++) acc[nt] = float4v{0.f,0.f,0.f,0.f};
  #pragma unroll
  for (int nt = 0; nt < 8; nt++){
    #pragma unroll
    for (int s = 0; s < KS; s++){
      short8 b = *(const short8*)(Wt_s + (nt*16 + l15)*LDP + s*32 + quad*8);
      acc[nt] = __builtin_amdgcn_mfma_f32_16x16x32_bf16(a[s], b, acc[nt], 0, 0, 0);
    }
  }

  // al/ar at this lane's columns (col = nt*16 + l15); H==1: heads>0 are zero
  float alc[8], arc[8];
  #pragma unroll
  for (int nt = 0; nt < 8; nt++){
    bool hv = (H == 2) || (nt < 4);
    alc[nt] = hv ? al[nt*16 + l15] : 0.f;
    arc[nt] = hv ? ar[nt*16 + l15] : 0.f;
  }
  #pragma unroll
  for (int reg = 0; reg < 4; reg++){
    int row = row0 + quad*4 + reg;
    bool rv = row < N;
    if (rv){
      #pragma unroll
      for (int nt = 0; nt < 8; nt++)
        fhb[(size_t)row*128 + nt*16 + l15] = f2h(acc[nt][reg]);
    }
    float pel0 = 0.f, per0 = 0.f, pel1 = 0.f, per1 = 0.f;
    #pragma unroll
    for (int nt = 0; nt < 4; nt++){
      pel0 += acc[nt][reg]*alc[nt];     per0 += acc[nt][reg]*arc[nt];
      pel1 += acc[nt+4][reg]*alc[nt+4]; per1 += acc[nt+4][reg]*arc[nt+4];
    }
    #pragma unroll
    for (int off = 1; off < 16; off <<= 1){   // reduce across the 16 lanes of a quad
      pel0 += __shfl_xor(pel0, off, 64);
      pel1 += __shfl_xor(pel1, off, 64);
      per0 += __shfl_xor(per0, off, 64);
      per1 += __shfl_xor(per1, off, 64);
    }
    if (l15 == 0 && rv){
      elr[row*4+0] = pel0;
      elr[row*4+1] = (H == 2) ? pel1 : 0.f;
      elr[row*4+2] = per0;
      elr[row*4+3] = (H == 2) ? per1 : 0.f;
    }
  }
}

// GROUP-PER-NODE aggregation: block = 256 thr = 16 groups of 16 lanes; each
// group owns ONE node and streams its edges. Lane c holds a 16B (H=2, full
// 256B row) / 8B (H=1, cols 0..63) chunk. alpha computed inline per edge
// (same value in all 16 lanes of the group — no cross-lane ops anywhere).
// den accumulates identically per lane -> epilogue reciprocal needs no reduce.
// 4-deep main loop: 4 independent ssrc->elr->row chains, 12 VMEM in flight.
template<int H>
__global__ __launch_bounds__(256) void k_agg_gp(
    const unsigned short* __restrict__ fhb,  // [N][128] f16
    const float* __restrict__ elr,           // [N][4]
    const int* __restrict__ row_ptr, const int* __restrict__ ssrc,
    const float* __restrict__ bias, const float* __restrict__ res,
    int act, int res_from_fh,
    float* __restrict__ out, int out_ld, unsigned* __restrict__ outb, int N){
  const int t = threadIdx.x;
  const int gq = t >> 4, c = t & 15;         // group, lane-in-group
  const int n = blockIdx.x*16 + gq;
  if (n >= N) return;
  const int beg = row_ptr[n], end = row_ptr[n+1];
  const float er0 = elr[n*4+2];
  const float er1 = (H == 2) ? elr[n*4+3] : 0.f;

  const char* fhbB = (const char*)fhb;       // row = 256 B, 32-bit offsets
  const unsigned cb = (H == 2) ? ((unsigned)c << 4) : ((unsigned)c << 3);
  constexpr int PC = (H == 2) ? 8 : 4;       // cols per lane

  float acc[PC];
  #pragma unroll
  for (int k = 0; k < PC; k++) acc[k] = 0.f;
  float den0 = 0.f, den1 = 0.f;

  int i = beg;
  for (; i + 3 < end; i += 4){               // 4-deep: 4 independent chains
    int s0 = ssrc[i],   s1 = ssrc[i+1];
    int s2 = ssrc[i+2], s3 = ssrc[i+3];
    float2 el0 = *(const float2*)(elr + s0*4);
    float2 el1 = *(const float2*)(elr + s1*4);
    float2 el2 = *(const float2*)(elr + s2*4);
    float2 el3 = *(const float2*)(elr + s3*4);
    if (H == 2){
      uint4 w0 = *(const uint4*)(fhbB + (((unsigned)s0 << 8) + cb));
      uint4 w1 = *(const uint4*)(fhbB + (((unsigned)s1 << 8) + cb));
      uint4 w2 = *(const uint4*)(fhbB + (((unsigned)s2 << 8) + cb));
      uint4 w3 = *(const uint4*)(fhbB + (((unsigned)s3 << 8) + cb));
      float e00 = __expf(fminf(lrelu(el0.x + er0), 30.f));
      float e10 = __expf(fminf(lrelu(el1.x + er0), 30.f));
      float e20 = __expf(fminf(lrelu(el2.x + er0), 30.f));
      float e30 = __expf(fminf(lrelu(el3.x + er0), 30.f));
      float e01 = __expf(fminf(lrelu(el0.y + er1), 30.f));
      float e11 = __expf(fminf(lrelu(el1.y + er1), 30.f));
      float e21 = __expf(fminf(lrelu(el2.y + er1), 30.f));
      float e31 = __expf(fminf(lrelu(el3.y + er1), 30.f));
      den0 += (e00 + e10) + (e20 + e30);
      den1 += (e01 + e11) + (e21 + e31);
      float a0 = (c < 8) ? e00 : e01;        // head = col/64
      float a1 = (c < 8) ? e10 : e11;
      float a2 = (c < 8) ? e20 : e21;
      float a3 = (c < 8) ? e30 : e31;
      const __half2* h0 = (const __half2*)&w0;
      const __half2* h1 = (const __half2*)&w1;
      const __half2* h2 = (const __half2*)&w2;
      const __half2* h3 = (const __half2*)&w3;
      #pragma unroll
      for (int q = 0; q < 4; q++){
        acc[2*q]   = fmaf((float)h0[q].x, a0, acc[2*q]);
        acc[2*q+1] = fmaf((float)h0[q].y, a0, acc[2*q+1]);
        acc[2*q]   = fmaf((float)h1[q].x, a1, acc[2*q]);
        acc[2*q+1] = fmaf((float)h1[q].y, a1, acc[2*q+1]);
        acc[2*q]   = fmaf((float)h2[q].x, a2, acc[2*q]);
        acc[2*q+1] = fmaf((float)h2[q].y, a2, acc[2*q+1]);
        acc[2*q]   = fmaf((float)h3[q].x, a3, acc[2*q]);
        acc[2*q+1] = fmaf((float)h3[q].y, a3, acc[2*q+1]);
      }
    } else {
      uint2 w0 = *(const uint2*)(fhbB + (((unsigned)s0 << 8) + cb));
      uint2 w1 = *(const uint2*)(fhbB + (((unsigned)s1 << 8) + cb));
      uint2 w2 = *(const uint2*)(fhbB + (((unsigned)s2 << 8) + cb));
      uint2 w3 = *(const uint2*)(fhbB + (((unsigned)s3 << 8) + cb));
      float e00 = __expf(fminf(lrelu(el0.x + er0), 30.f));
      float e10 = __expf(fminf(lrelu(el1.x + er0), 30.f));
      float e20 = __expf(fminf(lrelu(el2.x + er0), 30.f));
      float e30 = __expf(fminf(lrelu(el3.x + er0), 30.f));
      den0 += (e00 + e10) + (e20 + e30);
      const __half2* h0 = (const __half2*)&w0;
      const __half2* h1 = (const __half2*)&w1;
      const __half2* h2 = (const __half2*)&w2;
      const __half2* h3 = (const __half2*)&w3;
      #pragma unroll
      for (int q = 0; q < 2; q++){
        acc[2*q]   = fmaf((float)h0[q].x, e00, acc[2*q]);
        acc[2*q+1] = fmaf((float)h0[q].y, e00, acc[2*q+1]);
        acc[2*q]   = fmaf((float)h1[q].x, e10, acc[2*q]);
        acc[2*q+1] = fmaf((float)h1[q].y, e10, acc[2*q+1]);
        acc[2*q]   = fmaf((float)h2[q].x, e20, acc[2*q]);
        acc[2*q+1] = fmaf((float)h2[q].y, e20, acc[2*q+1]);
        acc[2*q]   = fmaf((float)h3[q].x, e30, acc[2*q]);
        acc[2*q+1] = fmaf((float)h3[q].y, e30, acc[2*q+1]);
      }
    }
  }
  for (; i < end; i++){                      // tail: 0-3 edges
    int s0 = ssrc[i];
    float2 el0 = *(const float2*)(elr + s0*4);
    float e00 = __expf(fminf(lrelu(el0.x + er0), 30.f));
    float e01 = (H == 2) ? __expf(fminf(lrelu(el0.y + er1), 30.f)) : 0.f;
    den0 += e00; den1 += e01;
    if (H == 2){
      uint4 w0 = *(const uint4*)(fhbB + (((unsigned)s0 << 8) + cb));
      float a0 = (c < 8) ? e00 : e01;
      const __half2* h0 = (const __half2*)&w0;
      #pragma unroll
      for (int q = 0; q < 4; q++){
        acc[2*q]   = fmaf((float)h0[q].x, a0, acc[2*q]);
        acc[2*q+1] = fmaf((float)h0[q].y, a0, acc[2*q+1]);
      }
    } else {
      uint2 w0 = *(const uint2*)(fhbB + (((unsigned)s0 << 8) + cb));
      const __half2* h0 = (const __half2*)&w0;
      #pragma unroll
      for (int q = 0; q < 2; q++){
        acc[2*q]   = fmaf((float)h0[q].x, e00, acc[2*q]);
        acc[2*q+1] = fmaf((float)h0[q].y, e00, acc[2*q+1]);
      }
    }
  }

  // epilogue: den identical across the group's lanes — no reduce needed.
  float rd0 = den0 > 0.f ? 1.f/den0 : 0.f;
  float rd1 = (H == 2 && den1 > 0.f) ? 1.f/den1 : 0.f;

  if (H == 2){
    float rs = (c < 8) ? rd0 : rd1;
    float o[8];
    const float4* b4 = (const float4*)(bias + c*8);
    float4 ba = b4[0], bb = b4[1];
    o[0]=fmaf(acc[0],rs,ba.x); o[1]=fmaf(acc[1],rs,ba.y);
    o[2]=fmaf(acc[2],rs,ba.z); o[3]=fmaf(acc[3],rs,ba.w);
    o[4]=fmaf(acc[4],rs,bb.x); o[5]=fmaf(acc[5],rs,bb.y);
    o[6]=fmaf(acc[6],rs,bb.z); o[7]=fmaf(acc[7],rs,bb.w);
    if (res){
      const float4* r4 = (const float4*)(res + (size_t)n*128 + c*8);
      float4 ra = r4[0], rb = r4[1];
      o[0]+=ra.x; o[1]+=ra.y; o[2]+=ra.z; o[3]+=ra.w;
      o[4]+=rb.x; o[5]+=rb.y; o[6]+=rb.z; o[7]+=rb.w;
    }
    if (act){
      #pragma unroll
      for (int k = 0; k < 8; k++) o[k] = elu1(o[k]);
    }
    if (out){
      float4* o4 = (float4*)(out + (size_t)n*out_ld + c*8);
      o4[0] = make_float4(o[0], o[1], o[2], o[3]);
      o4[1] = make_float4(o[4], o[5], o[6], o[7]);
    }
    if (outb){
      uint4 ob;
      ob.x = (unsigned)f2bf(o[0]) | ((unsigned)f2bf(o[1]) << 16);
      ob.y = (unsigned)f2bf(o[2]) | ((unsigned)f2bf(o[3]) << 16);
      ob.z = (unsigned)f2bf(o[4]) | ((unsigned)f2bf(o[5]) << 16);
      ob.w = (unsigned)f2bf(o[6]) | ((unsigned)f2bf(o[7]) << 16);
      *(uint4*)(outb + (size_t)n*64 + c*4) = ob;
    }
  } else {
    float o[4];
    #pragma unroll
    for (int k = 0; k < 4; k++) o[k] = fmaf(acc[k], rd0, bias[c*4 + k]);
    if (res_from_fh){
      uint2 r = *(const uint2*)(fhbB + (size_t)n*256 + 128 + c*8);
      const __half2* rp = (const __half2*)&r;
      o[0] += (float)rp[0].x; o[1] += (float)rp[0].y;
      o[2] += (float)rp[1].x; o[3] += (float)rp[1].y;
    }
    if (act){
      #pragma unroll
      for (int k = 0; k < 4; k++) o[k] = elu1(o[k]);
    }
    *(float4*)(out + (size_t)n*out_ld + c*4) = make_float4(o[0], o[1], o[2], o[3]);
  }
}

extern "C" void kernel_launch(void* const* d_in, const int* in_sizes, int n_in,
                              void* d_out, int out_size, void* d_ws, size_t ws_size,
                              hipStream_t stream) {
  const int*   feat = (const int*)  d_in[0];
  const float* fv   = (const float*)d_in[1];
  const int*   src  = (const int*)  d_in[2];
  const int*   dst  = (const int*)  d_in[3];
  const float* emb  = (const float*)d_in[4];
  const float* W0   = (const float*)d_in[5];
  const float* al0  = (const float*)d_in[6];
  const float* ar0  = (const float*)d_in[7];
  const float* b0   = (const float*)d_in[8];
  const float* W1   = (const float*)d_in[9];
  const float* al1  = (const float*)d_in[10];
  const float* ar1  = (const float*)d_in[11];
  const float* b1   = (const float*)d_in[12];
  const float* W2   = (const float*)d_in[13];
  const float* al2  = (const float*)d_in[14];
  const float* ar2  = (const float*)d_in[15];
  const float* b2   = (const float*)d_in[16];
  const float* rW2  = (const float*)d_in[17];
  const int N = in_sizes[0] / 8;   // 50000
  const int E = in_sizes[2];       // 800000

  size_t off = 0;
  auto alloc = [&](size_t bytes) -> void* {
    void* p = (char*)d_ws + off;
    off = (off + bytes + 255) & ~(size_t)255;
    return p;
  };
  unsigned short* P1 = (unsigned short*)alloc((size_t)N*128*sizeof(unsigned short)); // fhb f16
  float* P2     = (float*)alloc((size_t)N*128*sizeof(float));                        // layer0 out (res for layer1)
  unsigned short* hb = (unsigned short*)alloc((size_t)N*128*sizeof(unsigned short)); // h bf16
  float* elr    = (float*)alloc((size_t)N*4*sizeof(float));
  int* row_ptr  = (int*)alloc((size_t)(N+1)*sizeof(int));
  int* counts   = (int*)alloc((size_t)N*sizeof(int));
  int* rank     = (int*)alloc((size_t)E*sizeof(int));
  int* ssrc     = (int*)alloc((size_t)E*sizeof(int));
  int* bsum     = (int*)alloc(256*sizeof(int));
  unsigned short* Wt0 = (unsigned short*)alloc((size_t)128*64*sizeof(unsigned short));
  unsigned short* Wt1 = (unsigned short*)alloc((size_t)128*128*sizeof(unsigned short));
  unsigned short* Wt2 = (unsigned short*)alloc((size_t)128*128*sizeof(unsigned short));

  int nb1 = (N + 255) / 256;
  int eb  = (E + 255) / 256;
  // setup: zero counts + weight preps (one launch)
  k_setup<<<(N + 128*64 + 2*128*128 + 255)/256, 256, 0, stream>>>(
      counts, N, W0, W1, W2, rW2, Wt0, Wt1, Wt2);
  // CSR build (rank captured in hist atomic; scatter atomic-free)
  k_hist_rank<<<eb, 256, 0, stream>>>(dst, counts, rank, E);
  k_scan_local<<<nb1, 256, 0, stream>>>(counts, row_ptr, bsum, N);
  k_scan_top<<<1, 256, 0, stream>>>(bsum, nb1);
  k_scan_fix<<<nb1, 256, 0, stream>>>(row_ptr, bsum, N);
  k_scatter2<<<eb, 256, 0, stream>>>(src, dst, rank, row_ptr, ssrc, E);

  int gt  = (N + 63)/64;
  int ngp = (N + 15)/16;
  // layer 0: in=64, H=2, embed fused into A-load, no residual, elu
  k_gemm_mfma<64,2,true><<<gt, 256, 0, stream>>>(nullptr, feat, fv, emb,
                                                 Wt0, al0, ar0, P1, elr, N);
  k_agg_gp<2><<<ngp, 256, 0, stream>>>(P1, elr, row_ptr, ssrc, b0, nullptr,
                                       1, 0, P2, 128, (unsigned*)hb, N);
  // layer 1: in=128, H=2, identity residual, elu; float out unused -> skip store
  k_gemm_mfma<128,2,false><<<gt, 256, 0, stream>>>(hb, nullptr, nullptr, nullptr,
                                                   Wt1, al1, ar1, P1, elr, N);
  k_agg_gp<2><<<ngp, 256, 0, stream>>>(P1, elr, row_ptr, ssrc, b1, P2,
                                       1, 0, nullptr, 128, (unsigned*)hb, N);
  // layer 2: in=128, H=1, projected residual (fh cols 64..127 = h@resW2), no act
  k_gemm_mfma<128,1,false><<<gt, 256, 0, stream>>>(hb, nullptr, nullptr, nullptr,
                                                   Wt2, al2, ar2, P1, elr, N);
  k_agg_gp<1><<<ngp, 256, 0, stream>>>(P1, elr, row_ptr, ssrc, b2, nullptr,
                                       0, 1, (float*)d_out, 64, nullptr, N);
}